// Round 1
// baseline (128.129 us; speedup 1.0000x reference)
//
#include <hip/hip_runtime.h>

// BinarySplitDecoder: out[b][j] = prod_{d=0}^{9} f(x[b][(2^d-1) + (j>>(10-d))]),
// f = a if path bit ((j>>(9-d))&1)==0 else (1-a).
// B = 65536 rows, 1023 internal nodes/row, 1024 leaves/row. Memory-bound:
// 256 MB read + 256 MB write -> ~81 us floor at 6.3 TB/s.

#define N_INTERNAL 1023
#define N_LEAVES   1024

__global__ __launch_bounds__(256) void bsd_kernel(const float* __restrict__ x,
                                                  float* __restrict__ out,
                                                  int B) {
    __shared__ float lds[N_INTERNAL];
    const int row = blockIdx.x;
    if (row >= B) return;
    const int t = threadIdx.x;

    // Stage the row (1023 floats) into LDS, coalesced dword loads.
    const float* __restrict__ xr = x + (size_t)row * N_INTERNAL;
    for (int k = t; k < N_INTERNAL; k += 256) lds[k] = xr[k];
    __syncthreads();

    // Thread t computes leaves j = 4t .. 4t+3.
    // Levels 0..7: node = t >> (8-d), choice bit = (t >> (7-d)) & 1 — shared
    // prefix across the 4 leaves.
    float p = 1.0f;
#pragma unroll
    for (int d = 0; d < 8; ++d) {
        const int node = t >> (8 - d);
        const float a = lds[(1 << d) - 1 + node];
        const int bit = (t >> (7 - d)) & 1;
        p *= bit ? (1.0f - a) : a;
    }

    // Level 8: node = t (base 255), bit = (i>>1).
    // Level 9: node = 2t + (i>>1) (base 511), bit = i&1.
    const float a8   = lds[255 + t];
    const float a9_0 = lds[511 + 2 * t];
    const float a9_1 = lds[511 + 2 * t + 1];

    const float pl = p * a8;           // leaves i=0,1
    const float pr = p * (1.0f - a8);  // leaves i=2,3

    float4 o;
    o.x = pl * a9_0;
    o.y = pl * (1.0f - a9_0);
    o.z = pr * a9_1;
    o.w = pr * (1.0f - a9_1);

    // j = 4t..4t+3 -> one aligned float4 store per thread, fully coalesced.
    float4* __restrict__ op = (float4*)(out + (size_t)row * N_LEAVES);
    op[t] = o;
}

extern "C" void kernel_launch(void* const* d_in, const int* in_sizes, int n_in,
                              void* d_out, int out_size, void* d_ws, size_t ws_size,
                              hipStream_t stream) {
    const float* x = (const float*)d_in[0];
    float* out = (float*)d_out;
    const int B = in_sizes[0] / N_INTERNAL;
    bsd_kernel<<<B, 256, 0, stream>>>(x, out, B);
}

// Round 2
// 82.562 us; speedup vs baseline: 1.5519x; 1.5519x over previous
//
#include <hip/hip_runtime.h>

// BinarySplitDecoder: out[b][j] = prod_{d=0}^{9} f(x[b][(2^d-1) + (j>>(10-d))]),
// f = a if path bit ((j>>(9-d))&1)==0 else (1-a).
// B = 65536 rows, 1023 internal/row, 1024 leaves/row.
// Memory-bound: 256 MB read + 256 MB write -> ~85 us floor at ~6 TB/s mixed.
//
// 4 rows per block: 4 rows of x = 4092 floats = 16368 B = 1023 * 16 B, so
// every 4-row group is 16B-aligned and an exact float4 count -> dwordx4
// staging loads (16 B/lane) instead of scalar dword (4 B/lane).

#define N_INTERNAL 1023
#define N_LEAVES   1024
#define RPB        4     // rows per block (B=65536 is divisible by 4)

typedef float f32x4 __attribute__((ext_vector_type(4)));

__global__ __launch_bounds__(256) void bsd_kernel(const float* __restrict__ x,
                                                  float* __restrict__ out,
                                                  int B) {
    __shared__ float lds[RPB * N_INTERNAL];   // 16368 B
    const int t = threadIdx.x;
    const size_t row0 = (size_t)blockIdx.x * RPB;

    if (row0 + RPB <= (size_t)B) {
        // Fast path: stage 4 contiguous rows as 1023 float4 loads.
        const f32x4* __restrict__ xv = (const f32x4*)(x + row0 * N_INTERNAL);
        f32x4* __restrict__ lv = (f32x4*)lds;
        for (int k = t; k < RPB * N_INTERNAL / 4; k += 256) lv[k] = xv[k];
    } else {
        // Tail path (unused for B=65536): scalar staging with bounds guard.
        const size_t nrem = ((size_t)B - row0) * N_INTERNAL;
        const float* __restrict__ xr = x + row0 * N_INTERNAL;
        for (int k = t; k < RPB * N_INTERNAL; k += 256)
            lds[k] = ((size_t)k < nrem) ? xr[k] : 0.0f;
    }
    __syncthreads();

#pragma unroll
    for (int r = 0; r < RPB; ++r) {
        if (row0 + r >= (size_t)B) break;
        const float* __restrict__ lr = lds + r * N_INTERNAL;

        // Thread t owns leaves 4t..4t+3 of row (row0+r).
        // Levels 0..7 share a prefix across the 4 leaves (path bits = bits of t).
        float p = 1.0f;
#pragma unroll
        for (int d = 0; d < 8; ++d) {
            const float a = lr[(1 << d) - 1 + (t >> (8 - d))];
            p *= ((t >> (7 - d)) & 1) ? (1.0f - a) : a;
        }

        const float a8  = lr[255 + t];          // level 8, node t
        const float a90 = lr[511 + 2 * t];      // level 9, node 2t
        const float a91 = lr[512 + 2 * t];      // level 9, node 2t+1

        const float pl = p * a8;
        const float pr = p * (1.0f - a8);

        f32x4 o;
        o.x = pl * a90;
        o.y = pl * (1.0f - a90);
        o.z = pr * a91;
        o.w = pr * (1.0f - a91);

        // Coalesced 16B nontemporal store; output is never re-read.
        f32x4* __restrict__ op = (f32x4*)(out + (row0 + r) * N_LEAVES);
        __builtin_nontemporal_store(o, op + t);
    }
}

extern "C" void kernel_launch(void* const* d_in, const int* in_sizes, int n_in,
                              void* d_out, int out_size, void* d_ws, size_t ws_size,
                              hipStream_t stream) {
    const float* x = (const float*)d_in[0];
    float* out = (float*)d_out;
    const int B = in_sizes[0] / N_INTERNAL;
    const int grid = (B + RPB - 1) / RPB;
    bsd_kernel<<<grid, 256, 0, stream>>>(x, out, B);
}